// Round 1
// baseline (147.524 us; speedup 1.0000x reference)
//
#include <hip/hip_runtime.h>

#define N_NODES 8192
#define N_EDGES 8192
#define DEG 32
#define NNZ (N_EDGES * DEG)
#define D 32

// ---------------------------------------------------------------------------
// K_fuse: collapse the affine MLP.
//   M = Wm1(64x32) @ Wm2(32x32) @ Wm3(32x1)  -> uc[0..63]
//   c = bm1 @ (Wm2@Wm3) + bm2 @ Wm3 + bm3    -> uc[64]
// ---------------------------------------------------------------------------
__global__ void k_fuse(const float* __restrict__ Wm1, const float* __restrict__ bm1,
                       const float* __restrict__ Wm2, const float* __restrict__ bm2,
                       const float* __restrict__ Wm3, const float* __restrict__ bm3,
                       float* __restrict__ uc) {
    __shared__ float w23[32];
    int t = threadIdx.x;  // 64 threads
    if (t < 32) {
        float s = 0.f;
        for (int k = 0; k < 32; ++k) s += Wm2[t * 32 + k] * Wm3[k];
        w23[t] = s;
    }
    __syncthreads();
    float s = 0.f;
    for (int k = 0; k < 32; ++k) s += Wm1[t * 32 + k] * w23[k];
    uc[t] = s;
    if (t == 0) {
        float c = bm3[0];
        for (int k = 0; k < 32; ++k) c += bm1[k] * w23[k] + bm2[k] * Wm3[k];
        uc[64] = c;
    }
}

// ---------------------------------------------------------------------------
// K_edgeagg: A[e] = sum over UNIQUE nodes of edge e of X[node].
// 256 threads = 8 edges/block; 32 threads per edge.
// Phase 1 computes (or loads) the per-edge first-occurrence validity mask.
// Phase 2: thread d accumulates column d over valid slots.
// ---------------------------------------------------------------------------
template <bool COMPUTE_MASK>
__global__ void k_edgeagg(const float* __restrict__ X, const int* __restrict__ node_idx,
                          float* __restrict__ A, unsigned* __restrict__ validmask) {
    __shared__ int sidx[8][32];
    __shared__ unsigned smask[8];
    int t = threadIdx.x;
    int el = t >> 5;
    int s = t & 31;
    int e = blockIdx.x * 8 + el;
    int idx = node_idx[e * DEG + s];
    sidx[el][s] = idx;
    __syncthreads();
    if (COMPUTE_MASK) {
        bool valid = true;
        for (int j = 0; j < s; ++j)
            if (sidx[el][j] == idx) { valid = false; break; }
        unsigned long long b = __ballot(valid);  // 64-bit, two edges per wave
        if (s == 0) {
            unsigned m = (unsigned)(b >> (t & 32));
            smask[el] = m;
            validmask[e] = m;
        }
    } else {
        if (s == 0) smask[el] = validmask[e];
    }
    __syncthreads();
    unsigned m = smask[el];
    int d = s;
    float acc = 0.f;
    for (int j = 0; j < 32; ++j) {
        if ((m >> j) & 1u) acc += X[sidx[el][j] * D + d];
    }
    A[e * D + d] = acc;
}

// ---------------------------------------------------------------------------
// K_atomicagg: B[n] += A[e] for every unique (n,e) incidence pair.
// One thread per (slot, d): 8M threads, 1 f32 atomic each (B is 1MB, L2-hot).
// ---------------------------------------------------------------------------
__global__ void k_atomicagg(const float* __restrict__ A, const int* __restrict__ node_idx,
                            const unsigned* __restrict__ validmask, float* __restrict__ B) {
    int gid = blockIdx.x * 256 + threadIdx.x;  // over NNZ*32
    int i = gid >> 5;   // slot
    int d = gid & 31;
    int e = i >> 5;
    int s = i & 31;
    if ((validmask[e] >> s) & 1u) {
        atomicAdd(&B[node_idx[i] * D + d], A[e * D + d]);
    }
}

// ---------------------------------------------------------------------------
// K_transform: X = B @ W (W is 32x32, staged in LDS). One thread per output.
// ---------------------------------------------------------------------------
__global__ void k_transform(const float* __restrict__ B, const float* __restrict__ W,
                            float* __restrict__ X) {
    __shared__ float sW[1024];
    int t = threadIdx.x;
    for (int k = t; k < 1024; k += 256) sW[k] = W[k];
    __syncthreads();
    int gid = blockIdx.x * 256 + t;  // over N_NODES * D
    int n = gid >> 5;
    int d = gid & 31;
    float acc = 0.f;
    for (int k = 0; k < 32; ++k) acc += B[n * 32 + k] * sW[k * 32 + d];
    X[gid] = acc;
}

// ---------------------------------------------------------------------------
// K_pq: p[n] = X2[n]·uc[0:32] + c ;  q[e] = A2[e]·uc[32:64]
// ---------------------------------------------------------------------------
__global__ void k_pq(const float* __restrict__ X2, const float* __restrict__ A2,
                     const float* __restrict__ uc, float* __restrict__ p,
                     float* __restrict__ q) {
    int gid = blockIdx.x * 256 + threadIdx.x;  // 16384 = N + E
    if (gid < N_NODES) {
        float acc = uc[64];
        for (int k = 0; k < 32; ++k) acc += X2[gid * 32 + k] * uc[k];
        p[gid] = acc;
    } else {
        int e = gid - N_NODES;
        float acc = 0.f;
        for (int k = 0; k < 32; ++k) acc += A2[e * 32 + k] * uc[32 + k];
        q[e] = acc;
    }
}

// ---------------------------------------------------------------------------
// K_scatter: out[n,e] = p[n] + q[e] for every nnz slot (duplicates write the
// same value, so no dedup needed on the write side).
// ---------------------------------------------------------------------------
__global__ void k_scatter(const int* __restrict__ node_idx, const float* __restrict__ p,
                          const float* __restrict__ q, float* __restrict__ out) {
    int i = blockIdx.x * 256 + threadIdx.x;  // slot in [0, NNZ)
    int e = i >> 5;
    int n = node_idx[i];
    out[(size_t)n * N_EDGES + e] = p[n] + q[e];
}

extern "C" void kernel_launch(void* const* d_in, const int* in_sizes, int n_in,
                              void* d_out, int out_size, void* d_ws, size_t ws_size,
                              hipStream_t stream) {
    const float* x0  = (const float*)d_in[0];
    // d_in[1] = dense incidence matrix: intentionally unused (sparse path).
    const float* Wl1 = (const float*)d_in[2];
    const float* Wl2 = (const float*)d_in[3];
    const float* Wm1 = (const float*)d_in[4];
    const float* bm1 = (const float*)d_in[5];
    const float* Wm2 = (const float*)d_in[6];
    const float* bm2 = (const float*)d_in[7];
    const float* Wm3 = (const float*)d_in[8];
    const float* bm3 = (const float*)d_in[9];
    const int* node_idx = (const int*)d_in[10];
    float* out = (float*)d_out;

    // Workspace layout (floats / words)
    char* ws = (char*)d_ws;
    float* A   = (float*)(ws);                          // [E*D]  1 MB (A1 then A2)
    float* B   = (float*)(ws + (1u << 20));             // [N*D]  1 MB
    float* X   = (float*)(ws + (2u << 20));             // [N*D]  1 MB (X1 then X2)
    float* p   = (float*)(ws + (3u << 20));             // [N]    32 KB
    float* q   = (float*)(ws + (3u << 20) + (32u << 10));  // [E] 32 KB
    unsigned* validmask = (unsigned*)(ws + (3u << 20) + (64u << 10));  // [E] 32 KB
    float* uc  = (float*)(ws + (3u << 20) + (96u << 10));  // [65]

    // Zero the 256 MB dense output (dominant cost; must happen every call).
    hipMemsetAsync(out, 0, (size_t)out_size * sizeof(float), stream);

    // Collapse the affine MLP.
    k_fuse<<<1, 64, 0, stream>>>(Wm1, bm1, Wm2, bm2, Wm3, bm3, uc);

    // Layer 1: A1 = inc^T x0 ; B1 = inc A1 ; X1 = B1 @ W_l1
    k_edgeagg<true><<<N_EDGES / 8, 256, 0, stream>>>(x0, node_idx, A, validmask);
    hipMemsetAsync(B, 0, N_NODES * D * sizeof(float), stream);
    k_atomicagg<<<(NNZ * D) / 256, 256, 0, stream>>>(A, node_idx, validmask, B);
    k_transform<<<(N_NODES * D) / 256, 256, 0, stream>>>(B, Wl1, X);

    // Layer 2: A2 = inc^T X1 ; B2 = inc A2 ; X2 = B2 @ W_l2
    k_edgeagg<false><<<N_EDGES / 8, 256, 0, stream>>>(X, node_idx, A, validmask);
    hipMemsetAsync(B, 0, N_NODES * D * sizeof(float), stream);
    k_atomicagg<<<(NNZ * D) / 256, 256, 0, stream>>>(A, node_idx, validmask, B);
    k_transform<<<(N_NODES * D) / 256, 256, 0, stream>>>(B, Wl2, X);

    // Collapsed MLP: per-node / per-edge dot products, then scatter.
    k_pq<<<(N_NODES + N_EDGES) / 256, 256, 0, stream>>>(X, A, uc, p, q);
    k_scatter<<<NNZ / 256, 256, 0, stream>>>(node_idx, p, q, out);
}

// Round 2
// 145.210 us; speedup vs baseline: 1.0159x; 1.0159x over previous
//
#include <hip/hip_runtime.h>

#define N_NODES 8192
#define N_EDGES 8192
#define DEG 32
#define NNZ (N_EDGES * DEG)
#define D 32

// ---------------------------------------------------------------------------
// k_fuse: collapse the affine MLP and precompute layer-2 folds.
//   uc[0:64] = Wm1 @ (Wm2 @ Wm3), uc[64] = bm1@(Wm2@Wm3) + bm2@Wm3 + bm3
//   w2u[k]   = sum_d W_l2[k,d] * uc[d]   (so p[n] = uc64 + B2[n]·w2u)
// ---------------------------------------------------------------------------
__global__ void k_fuse(const float* __restrict__ Wm1, const float* __restrict__ bm1,
                       const float* __restrict__ Wm2, const float* __restrict__ bm2,
                       const float* __restrict__ Wm3, const float* __restrict__ bm3,
                       const float* __restrict__ Wl2,
                       float* __restrict__ uc, float* __restrict__ w2u) {
    __shared__ float w23[32];
    __shared__ float m1[32];
    int t = threadIdx.x;  // 64 threads
    if (t < 32) {
        float s = 0.f;
        for (int k = 0; k < 32; ++k) s += Wm2[t * 32 + k] * Wm3[k];
        w23[t] = s;
    }
    __syncthreads();
    float s = 0.f;
    for (int k = 0; k < 32; ++k) s += Wm1[t * 32 + k] * w23[k];
    uc[t] = s;
    if (t < 32) m1[t] = s;
    if (t == 0) {
        float c = bm3[0];
        for (int k = 0; k < 32; ++k) c += bm1[k] * w23[k] + bm2[k] * Wm3[k];
        uc[64] = c;
    }
    __syncthreads();
    if (t < 32) {
        float v = 0.f;
        for (int d = 0; d < 32; ++d) v += Wl2[t * 32 + d] * m1[d];
        w2u[t] = v;
    }
}

// ---------------------------------------------------------------------------
// k_edgeagg1: A1[e] = sum over UNIQUE nodes of edge e of x0[node].
// Also computes the per-edge validity mask (first-occurrence dedup) and the
// per-node valid-degree histogram (for CSR build).
// 256 threads = 8 edges/block; 32 threads per edge.
// ---------------------------------------------------------------------------
__global__ void k_edgeagg1(const float* __restrict__ X, const int* __restrict__ node_idx,
                           float* __restrict__ A, unsigned* __restrict__ validmask,
                           int* __restrict__ counts) {
    __shared__ int sidx[8][32];
    __shared__ unsigned smask[8];
    int t = threadIdx.x;
    int el = t >> 5;
    int s = t & 31;
    int e = blockIdx.x * 8 + el;
    int idx = node_idx[e * DEG + s];
    sidx[el][s] = idx;
    __syncthreads();
    bool valid = true;
    for (int j = 0; j < s; ++j)
        if (sidx[el][j] == idx) { valid = false; break; }
    unsigned long long b = __ballot(valid);
    if (s == 0) {
        unsigned m = (unsigned)(b >> (t & 32));
        smask[el] = m;
        validmask[e] = m;
    }
    if (valid) atomicAdd(&counts[idx], 1);
    __syncthreads();
    unsigned m = smask[el];
    float acc = 0.f;
    for (int j = 0; j < 32; ++j) {
        if ((m >> j) & 1u) acc += X[sidx[el][j] * D + s];
    }
    A[e * D + s] = acc;
}

// ---------------------------------------------------------------------------
// k_scan: exclusive prefix sum of counts[8192] -> off[8193]; cursor = off copy.
// Single block, 1024 threads, 8 counts/thread.
// ---------------------------------------------------------------------------
__global__ void k_scan(const int* __restrict__ counts, int* __restrict__ off,
                       int* __restrict__ cursor) {
    __shared__ int ls[1024];
    int t = threadIdx.x;
    int c[8];
    int ts = 0;
    for (int j = 0; j < 8; ++j) { c[j] = counts[t * 8 + j]; ts += c[j]; }
    ls[t] = ts;
    __syncthreads();
    for (int sft = 1; sft < 1024; sft <<= 1) {
        int v = (t >= sft) ? ls[t - sft] : 0;
        __syncthreads();
        ls[t] += v;
        __syncthreads();
    }
    int base = ls[t] - ts;
    for (int j = 0; j < 8; ++j) {
        off[t * 8 + j] = base;
        cursor[t * 8 + j] = base;
        base += c[j];
    }
    if (t == 1023) off[8192] = ls[1023];
}

// ---------------------------------------------------------------------------
// k_csrfill: csr_e[] = edge ids grouped by node (valid slots only).
// ---------------------------------------------------------------------------
__global__ void k_csrfill(const int* __restrict__ node_idx, const unsigned* __restrict__ validmask,
                          int* __restrict__ cursor, int* __restrict__ csr_e) {
    int i = blockIdx.x * 256 + threadIdx.x;  // slot in [0, NNZ)
    int e = i >> 5;
    int s = i & 31;
    if ((validmask[e] >> s) & 1u) {
        int pos = atomicAdd(&cursor[node_idx[i]], 1);
        csr_e[pos] = e;
    }
}

// ---------------------------------------------------------------------------
// k_nodeagg_tf: X1[n] = (sum_{e in CSR[n]} A1[e]) @ W  (W staged in LDS).
// 8 nodes/block, 32 threads (one per column) per node. No atomics.
// ---------------------------------------------------------------------------
__global__ void k_nodeagg_tf(const float* __restrict__ A, const int* __restrict__ csr_e,
                             const int* __restrict__ off, const float* __restrict__ W,
                             float* __restrict__ X) {
    __shared__ float sW[1024];
    __shared__ float sB[8][32];
    int t = threadIdx.x;
    for (int k = t; k < 1024; k += 256) sW[k] = W[k];
    int el = t >> 5;
    int d = t & 31;
    int n = blockIdx.x * 8 + el;
    int base = off[n], end = off[n + 1];
    float acc = 0.f;
    for (int j = base; j < end; ++j) acc += A[csr_e[j] * D + d];
    sB[el][d] = acc;
    __syncthreads();
    float x = 0.f;
    for (int k = 0; k < 32; ++k) x += sB[el][k] * sW[k * 32 + d];
    X[n * D + d] = x;
}

// ---------------------------------------------------------------------------
// k_edgeagg2: A2[e] = sum over unique nodes of X1[node]; q[e] = A2[e]·uc[32:64].
// ---------------------------------------------------------------------------
__global__ void k_edgeagg2(const float* __restrict__ X, const int* __restrict__ node_idx,
                           const unsigned* __restrict__ validmask, const float* __restrict__ uc,
                           float* __restrict__ A, float* __restrict__ q) {
    __shared__ int sidx[8][32];
    int t = threadIdx.x;
    int el = t >> 5;
    int s = t & 31;
    int e = blockIdx.x * 8 + el;
    sidx[el][s] = node_idx[e * DEG + s];
    unsigned m = validmask[e];
    __syncthreads();
    float acc = 0.f;
    for (int j = 0; j < 32; ++j) {
        if ((m >> j) & 1u) acc += X[sidx[el][j] * D + s];
    }
    A[e * D + s] = acc;
    float v = acc * uc[32 + s];
    v += __shfl_xor(v, 16);
    v += __shfl_xor(v, 8);
    v += __shfl_xor(v, 4);
    v += __shfl_xor(v, 2);
    v += __shfl_xor(v, 1);
    if (s == 0) q[e] = v;
}

// ---------------------------------------------------------------------------
// k_nodeagg2: p[n] = uc[64] + (sum_{e in CSR[n]} A2[e]) · w2u.
// X2/B2 never materialized.
// ---------------------------------------------------------------------------
__global__ void k_nodeagg2(const float* __restrict__ A, const int* __restrict__ csr_e,
                           const int* __restrict__ off, const float* __restrict__ uc,
                           const float* __restrict__ w2u, float* __restrict__ p) {
    int t = threadIdx.x;
    int el = t >> 5;
    int d = t & 31;
    int n = blockIdx.x * 8 + el;
    int base = off[n], end = off[n + 1];
    float acc = 0.f;
    for (int j = base; j < end; ++j) acc += A[csr_e[j] * D + d];
    float v = acc * w2u[d];
    v += __shfl_xor(v, 16);
    v += __shfl_xor(v, 8);
    v += __shfl_xor(v, 4);
    v += __shfl_xor(v, 2);
    v += __shfl_xor(v, 1);
    if (d == 0) p[n] = v + uc[64];
}

// ---------------------------------------------------------------------------
// k_out: one block per node row. Stream 32 KB of zeros (float4), barrier
// (drains stores), then patch the row's incident cells while lines are
// L2-dirty. out[n,e] = p[n] + q[e].
// ---------------------------------------------------------------------------
__global__ void k_out(const int* __restrict__ csr_e, const int* __restrict__ off,
                      const float* __restrict__ p, const float* __restrict__ q,
                      float* __restrict__ out) {
    int n = blockIdx.x;
    int t = threadIdx.x;
    float4* row4 = (float4*)(out + (size_t)n * N_EDGES);
    float4 z = make_float4(0.f, 0.f, 0.f, 0.f);
#pragma unroll
    for (int k = 0; k < 8; ++k) row4[t + 256 * k] = z;
    __syncthreads();
    int base = off[n], end = off[n + 1];
    float pn = p[n];
    for (int j = base + t; j < end; j += 256) {
        int e = csr_e[j];
        out[(size_t)n * N_EDGES + e] = pn + q[e];
    }
}

extern "C" void kernel_launch(void* const* d_in, const int* in_sizes, int n_in,
                              void* d_out, int out_size, void* d_ws, size_t ws_size,
                              hipStream_t stream) {
    const float* x0  = (const float*)d_in[0];
    // d_in[1] = dense incidence matrix: unused (sparse path).
    const float* Wl1 = (const float*)d_in[2];
    const float* Wl2 = (const float*)d_in[3];
    const float* Wm1 = (const float*)d_in[4];
    const float* bm1 = (const float*)d_in[5];
    const float* Wm2 = (const float*)d_in[6];
    const float* bm2 = (const float*)d_in[7];
    const float* Wm3 = (const float*)d_in[8];
    const float* bm3 = (const float*)d_in[9];
    const int* node_idx = (const int*)d_in[10];
    float* out = (float*)d_out;

    // Workspace layout
    char* ws = (char*)d_ws;
    float*    A         = (float*)(ws);                          // 1 MB  [E*D]
    float*    X         = (float*)(ws + (1u << 20));             // 1 MB  [N*D]
    float*    p         = (float*)(ws + (2u << 20));             // 32 KB [N]
    float*    q         = (float*)(ws + (2u << 20) + ( 32u << 10));  // 32 KB [E]
    unsigned* validmask = (unsigned*)(ws + (2u << 20) + ( 64u << 10));  // 32 KB [E]
    int*      counts    = (int*)(ws + (2u << 20) + ( 96u << 10));  // 32 KB [N]
    int*      off       = (int*)(ws + (2u << 20) + (128u << 10));  // 64 KB [N+1]
    int*      cursor    = (int*)(ws + (2u << 20) + (192u << 10));  // 32 KB [N]
    float*    uc        = (float*)(ws + (2u << 20) + (224u << 10));  // 65
    float*    w2u       = (float*)(ws + (2u << 20) + (225u << 10));  // 32
    int*      csr_e     = (int*)(ws + (3u << 20));                // 1 MB [NNZ]

    hipMemsetAsync(counts, 0, N_NODES * sizeof(int), stream);
    k_fuse<<<1, 64, 0, stream>>>(Wm1, bm1, Wm2, bm2, Wm3, bm3, Wl2, uc, w2u);

    // Layer 1 edge agg + mask + degree histogram.
    k_edgeagg1<<<N_EDGES / 8, 256, 0, stream>>>(x0, node_idx, A, validmask, counts);
    // CSR build (node -> unique incident edges).
    k_scan<<<1, 1024, 0, stream>>>(counts, off, cursor);
    k_csrfill<<<NNZ / 256, 256, 0, stream>>>(node_idx, validmask, cursor, csr_e);
    // B1 = inc@A1 via CSR gather, fused X1 = B1@W_l1.
    k_nodeagg_tf<<<N_NODES / 8, 256, 0, stream>>>(A, csr_e, off, Wl1, X);
    // Layer 2: A2 (+ fused q), then p (X2/B2 folded away).
    k_edgeagg2<<<N_EDGES / 8, 256, 0, stream>>>(X, node_idx, validmask, uc, A, q);
    k_nodeagg2<<<N_NODES / 8, 256, 0, stream>>>(A, csr_e, off, uc, w2u, p);
    // Fused zero + patch output write (the 268 MB stream).
    k_out<<<N_NODES, 256, 0, stream>>>(csr_e, off, p, q, out);
}